// Round 2
// baseline (387.754 us; speedup 1.0000x reference)
//
#include <hip/hip_runtime.h>

// ---------------------------------------------------------------------------
// HolographicMemory fused: out = softmax(x @ [Kr|Ki]^T * temp) @ [Vr|Vi]
//   3 kernels: pack_x (fp32->bf16), pack_kv (concat+temp fold), fused
//   Fused: per block = 64 x-rows; energy acc register-resident (full 512 mem
//   cols), softmax via LDS-resident P, PV matmul reads P from LDS as A-frags.
// ---------------------------------------------------------------------------

#define DIMX    1024
#define MEMN    512
#define NROWS   32768
#define TEMP    0.04419417382415922f  // 512^-0.5
#define PSTRIDE 520                   // 512 + 8 pad: keeps 16B align, bank+4/row

typedef __bf16 bf16;
typedef __bf16 bf16x8 __attribute__((ext_vector_type(8)));
typedef float  f32x4  __attribute__((ext_vector_type(4)));

// async global->LDS, 16B/lane; LDS dest = wave-uniform base + lane*16
__device__ __forceinline__ void gload_lds16(const void* g, void* l) {
    __builtin_amdgcn_global_load_lds(
        (const __attribute__((address_space(1))) unsigned*)g,
        (__attribute__((address_space(3))) unsigned*)l,
        16, 0, 0);
}

// ---------------- pack x (fp32 -> bf16), 8 elems/thread --------------------
__global__ __launch_bounds__(256) void pack_x_kernel(const float* __restrict__ x,
                                                     bf16* __restrict__ xb) {
    const int i = (blockIdx.x * 256 + threadIdx.x) * 8;
    f32x4 a = *(const f32x4*)(x + i);
    f32x4 b = *(const f32x4*)(x + i + 4);
    bf16x8 o;
    o[0] = (bf16)a[0]; o[1] = (bf16)a[1]; o[2] = (bf16)a[2]; o[3] = (bf16)a[3];
    o[4] = (bf16)b[0]; o[5] = (bf16)b[1]; o[6] = (bf16)b[2]; o[7] = (bf16)b[3];
    *(bf16x8*)(xb + i) = o;
}

// --- pack K'*temp = [Kr|Ki] as [512][1024]; V'^T as [1024][512] (bf16) -----
__global__ __launch_bounds__(256) void pack_kv_kernel(const float* __restrict__ kr,
                                                      const float* __restrict__ ki,
                                                      const float* __restrict__ vr,
                                                      const float* __restrict__ vi,
                                                      bf16* __restrict__ Kb,
                                                      bf16* __restrict__ VbT) {
    const int idx = blockIdx.x * 256 + threadIdx.x;   // 0 .. 512*1024-1
    {   // Kb[m][h'] = temp * (h'<512 ? Kr[m][h'] : Ki[m][h'-512])
        const int m = idx >> 10, h = idx & 1023;
        const float v = (h < 512) ? kr[m * 512 + h] : ki[m * 512 + (h - 512)];
        Kb[idx] = (bf16)(v * TEMP);
    }
    {   // VbT[h'][m] : h'<512 -> Vr[m][h'], else Vi[m][h'-512]
        const int hp = idx >> 9, m = idx & 511;
        const float v = (hp < 512) ? vr[m * 512 + hp] : vi[m * 512 + (hp - 512)];
        VbT[idx] = (bf16)v;
    }
}

// ------------------------------ fused kernel -------------------------------
// 512 threads (8 waves), 64 x-rows per block, grid = 512 blocks.
// Phase 1: energy[64x512] = xb_tile @ Kb^T, acc register-resident
//          (wave w: rows 0..63 x cols w*64..+64, acc[4][4] f32x4 = 64 VGPR)
// softmax: exp (no max-sub; |logit|<0.2), unnormalized P -> LDS bf16,
//          1/rowsum kept in LDS, applied in epilogue
// Phase 2: out[64x1024] = P @ VbT^T in two 512-col chunks, A-frags from LDS
__global__ __launch_bounds__(512, 2) void fused_kernel(const bf16* __restrict__ xb,
                                                       const bf16* __restrict__ Kb,
                                                       const bf16* __restrict__ VbT,
                                                       float* __restrict__ out) {
    __shared__ bf16  Ps[64 * PSTRIDE];   // 66,560 B
    __shared__ bf16  As[64 * 32];        //  4,096 B
    __shared__ bf16  Bs[512 * 32];       // 32,768 B
    __shared__ float red[512];           //  2,048 B
    __shared__ float inv_row[64];        //    256 B   (total ~105.7 KB, 1 blk/CU)

    const int tid  = threadIdx.x;
    const int wave = tid >> 6, lane = tid & 63;
    const int lm   = lane & 15;          // m/n within 16-tile
    const int lkb  = (lane >> 4) * 8;    // k base within 32-chunk
    const int rowB = blockIdx.x * 64;

    f32x4 acc[4][4] = {};

    // ---------------- phase 1: energy = x_tile @ K'^T (K = 1024) ----------
    for (int k0 = 0; k0 < DIMX; k0 += 32) {
        __syncthreads();
        if (tid < 256)   // waves 0-3 stage A (64x32)
            gload_lds16(xb + (size_t)(rowB + (tid >> 2)) * DIMX + k0 + (tid & 3) * 8,
                        As + wave * 512);
        #pragma unroll
        for (int i = 0; i < 4; ++i)      // all waves stage B (512x32)
            gload_lds16(Kb + (size_t)(i * 128 + (tid >> 2)) * DIMX + k0 + (tid & 3) * 8,
                        Bs + i * 4096 + wave * 512);
        __syncthreads();

        bf16x8 af[4], bfj[4];
        #pragma unroll
        for (int i = 0; i < 4; ++i)
            af[i] = *(const bf16x8*)(As + (i * 16 + lm) * 32 + lkb);
        #pragma unroll
        for (int j = 0; j < 4; ++j)
            bfj[j] = *(const bf16x8*)(Bs + (wave * 64 + j * 16 + lm) * 32 + lkb);
        #pragma unroll
        for (int i = 0; i < 4; ++i)
            #pragma unroll
            for (int j = 0; j < 4; ++j)
                acc[i][j] = __builtin_amdgcn_mfma_f32_16x16x32_bf16(
                    af[i], bfj[j], acc[i][j], 0, 0, 0);
    }

    // write energy tile to Ps (C layout: col = lane&15, row = (lane>>4)*4+r)
    #pragma unroll
    for (int i = 0; i < 4; ++i)
        #pragma unroll
        for (int j = 0; j < 4; ++j)
            #pragma unroll
            for (int r = 0; r < 4; ++r)
                Ps[(i * 16 + (lane >> 4) * 4 + r) * PSTRIDE + wave * 64 + j * 16 + lm]
                    = (bf16)acc[i][j][r];
    __syncthreads();

    // ------------- softmax (unnormalized exp in-place, rowsum) -------------
    {
        const int row = tid & 63, q = tid >> 6;   // thread covers 64 cols
        bf16* p = Ps + row * PSTRIDE + q * 64;
        float s = 0.f;
        #pragma unroll
        for (int c = 0; c < 8; ++c) {
            bf16x8 v = *(const bf16x8*)(p + c * 8);
            bf16x8 e;
            #pragma unroll
            for (int u = 0; u < 8; ++u) {
                float ev = __expf((float)v[u]);
                s += ev;
                e[u] = (bf16)ev;
            }
            *(bf16x8*)(p + c * 8) = e;
        }
        red[tid] = s;
    }
    __syncthreads();
    if (tid < 64) {
        float s = 0.f;
        #pragma unroll
        for (int q = 0; q < 8; ++q) s += red[q * 64 + tid];
        inv_row[tid] = 1.0f / s;
    }
    __syncthreads();

    float myinv[4][4];
    #pragma unroll
    for (int i = 0; i < 4; ++i)
        #pragma unroll
        for (int r = 0; r < 4; ++r)
            myinv[i][r] = inv_row[i * 16 + (lane >> 4) * 4 + r];

    // ---------------- phase 2: out = P @ V'^T (K = 512), 2 chunks ----------
    for (int oc = 0; oc < 2; ++oc) {
        #pragma unroll
        for (int i = 0; i < 4; ++i)
            #pragma unroll
            for (int j = 0; j < 4; ++j)
                acc[i][j] = (f32x4){0.f, 0.f, 0.f, 0.f};

        for (int k0 = 0; k0 < MEMN; k0 += 32) {
            __syncthreads();
            #pragma unroll
            for (int i = 0; i < 4; ++i)   // stage V'^T rows [oc*512 .. +512]
                gload_lds16(VbT + (size_t)(oc * 512 + i * 128 + (tid >> 2)) * MEMN
                                + k0 + (tid & 3) * 8,
                            Bs + i * 4096 + wave * 512);
            __syncthreads();

            bf16x8 af[4], bfj[4];
            #pragma unroll
            for (int i = 0; i < 4; ++i)   // A-frags straight from Ps
                af[i] = *(const bf16x8*)(Ps + (i * 16 + lm) * PSTRIDE + k0 + lkb);
            #pragma unroll
            for (int j = 0; j < 4; ++j)
                bfj[j] = *(const bf16x8*)(Bs + (wave * 64 + j * 16 + lm) * 32 + lkb);
            #pragma unroll
            for (int i = 0; i < 4; ++i)
                #pragma unroll
                for (int j = 0; j < 4; ++j)
                    acc[i][j] = __builtin_amdgcn_mfma_f32_16x16x32_bf16(
                        af[i], bfj[j], acc[i][j], 0, 0, 0);
        }

        // epilogue: normalize + store fp32
        #pragma unroll
        for (int i = 0; i < 4; ++i)
            #pragma unroll
            for (int j = 0; j < 4; ++j)
                #pragma unroll
                for (int r = 0; r < 4; ++r)
                    out[(size_t)(rowB + i * 16 + (lane >> 4) * 4 + r) * DIMX
                        + oc * 512 + wave * 64 + j * 16 + lm]
                        = acc[i][j][r] * myinv[i][r];
    }
}

// ---------------------------------------------------------------------------
extern "C" void kernel_launch(void* const* d_in, const int* in_sizes, int n_in,
                              void* d_out, int out_size, void* d_ws, size_t ws_size,
                              hipStream_t stream) {
    const float* x  = (const float*)d_in[0];
    const float* kr = (const float*)d_in[1];
    const float* ki = (const float*)d_in[2];
    const float* vr = (const float*)d_in[3];
    const float* vi = (const float*)d_in[4];
    float* out = (float*)d_out;

    char* ws = (char*)d_ws;
    bf16* xb  = (bf16*)ws;                                  // 64 MiB
    bf16* Kb  = (bf16*)(ws + (size_t)67108864);             //  1 MiB
    bf16* VbT = (bf16*)(ws + (size_t)67108864 + 1048576);   //  1 MiB

    pack_x_kernel<<<16384, 256, 0, stream>>>(x, xb);
    pack_kv_kernel<<<2048, 256, 0, stream>>>(kr, ki, vr, vi, Kb, VbT);
    fused_kernel<<<512, 512, 0, stream>>>(xb, Kb, VbT, out);
}